// Round 7
// baseline (484.002 us; speedup 1.0000x reference)
//
#include <hip/hip_runtime.h>

typedef unsigned short u16;
typedef unsigned int   u32;
typedef short v8s __attribute__((ext_vector_type(8)));   // 8 bf16 (A/B frag, 4 VGPR)
typedef float v4f __attribute__((ext_vector_type(4)));   // 4 fp32 (C/D frag)

#define DEV __device__ __forceinline__
#define MFMA(a,b,c) __builtin_amdgcn_mfma_f32_16x16x32_bf16((a),(b),(c),0,0,0)

constexpr int Bb = 32, Tt = 64, Ff = 128, Dd = 64, Hh = 4, Kk = 32;

DEV u16 f2b(float f) {                       // RNE (prep kernel only)
    u32 u = __float_as_uint(f);
    return (u16)((u + 0x7fffu + ((u >> 16) & 1u)) >> 16);
}
DEV u32 pk2(float a, float b) {              // round-half-up pair pack (2 bf16 in u32)
    u32 x = __float_as_uint(a) + 0x8000u;
    u32 y = __float_as_uint(b) + 0x8000u;
    return (x >> 16) | (y & 0xffff0000u);
}

// ---- prep: convert all weights to bf16 containers in ws (128 KB) ----
// ws layout (u16):
//   [0, 49152)      : 6 proj  x [h][ch=32][d=64]   (tq,tk,tv,fq,fk,fv)
//   [49152, 65536)  : 2 woT   x [h][d=64][k=32]    (to, fo)
__global__ __launch_bounds__(256)
void prep_weights(const float* __restrict__ tq, const float* __restrict__ tk,
                  const float* __restrict__ tv, const float* __restrict__ fq,
                  const float* __restrict__ fk, const float* __restrict__ fv,
                  const float* __restrict__ to_, const float* __restrict__ fo,
                  u16* __restrict__ ws)
{
    int idx = blockIdx.x * 256 + threadIdx.x;          // 0..65535
    if (idx < 49152) {
        int p = idx >> 13, rem = idx & 8191;           // [h][ch][d]
        int h = rem >> 11, ch = (rem >> 6) & 31, d = rem & 63;
        const float* w = (p==0)?tq:(p==1)?tk:(p==2)?tv:(p==3)?fq:(p==4)?fk:fv;
        ws[idx] = f2b(w[d*128 + h*32 + ch]);           // w[d][h][ch]
    } else {
        int i2 = idx - 49152;
        int path = i2 >> 13, rem = i2 & 8191;          // [h][d][k]
        int h = rem >> 11, d = (rem >> 5) & 63, k2 = rem & 31;
        const float* w = path ? fo : to_;
        ws[idx] = f2b(w[h*2048 + k2*64 + d]);          // wo[h][k][d]
    }
}

// Fragment facts (HW-verified, learn_hip m89/m120):
//   A-frag: lane = A[m][k], m=lane&15, k=quad*8+j  (container row-major [m][k])
//   B-frag: lane = B[k][n], n=lane&15, k=quad*8+j  (container [n][k])
//   C/D:    lane = D[row][col], col=lane&15, row=quad*4+r
//   MFMA(A,B) -> D[m][n] = sum_k A[m][k]*B[n][k]; operand swap transposes D.
// MODE 0: temporal (NR=64 rows=T, block per (b,f)), writes fp32 partial.
// MODE 1: feature (NR=128 rows=F, block per (b,t)), read-add-write final.
template<int NR, int MODE>
__global__ __launch_bounds__(NR*4, 8)
void axial_mfma(const float* __restrict__ x, const u16* __restrict__ wsw,
                const float* __restrict__ bq, const float* __restrict__ bk,
                const float* __restrict__ bv, const float* __restrict__ bo,
                float* __restrict__ out)
{
    constexpr int W   = NR / 16;      // waves per block
    constexpr int QP  = 40;           // Q/K/O row pitch (80B: 16B-aligned)
    constexpr int NRp = NR + 8;       // V^T pitch (16B-aligned)
    constexpr int PSP = 40;           // P-slice row pitch
    constexpr int o_q  = 0;                   // Q, reused as O  [NR][QP]  (own-wave rows)
    constexpr int o_k  = o_q + NR * QP;       // K    [NR][QP]
    constexpr int o_vt = o_k + NR * QP;       // V^T  [32][NRp]
    constexpr int o_ps = o_vt + 32 * NRp;     // P-slice [W][16][PSP]  (wave-private)
    constexpr int SMEM = o_ps + W * 16 * PSP; // feature: 39424 B, temporal: 19968 B
    __shared__ alignas(16) u16 sm[SMEM];

    const int tid  = threadIdx.x;
    const int w    = tid >> 6;
    const int lane = tid & 63;
    const int quad = lane >> 4;
    const int l15  = lane & 15;
    const int bid  = blockIdx.x;

    int base, rstride;
    if (MODE == 0) { int b = bid >> 7, f = bid & 127; base = b*(Tt*Ff*Dd) + f*Dd; rstride = Ff*Dd; }
    else           { base = bid * (Ff*Dd); rstride = Dd; }

    constexpr int PB = (MODE == 0) ? 0 : 3;
    const u16* wql = wsw + (PB+0)*8192;
    const u16* wkl = wsw + (PB+1)*8192;
    const u16* wvl = wsw + (PB+2)*8192;
    const u16* wol = wsw + 49152 + MODE*8192;

    // ---- X fragments (A/B dual-use; same lane mapping), row w*16+l15 ----
    v8s xfrag[2];
#pragma unroll
    for (int ks = 0; ks < 2; ++ks) {
        const float* xp = x + base + (w*16 + l15)*rstride + ks*32 + quad*8;
        float4 a = *reinterpret_cast<const float4*>(xp);
        float4 b = *reinterpret_cast<const float4*>(xp + 4);
        v8s f;
        u32* fu = reinterpret_cast<u32*>(&f);
        fu[0] = pk2(a.x, a.y); fu[1] = pk2(a.z, a.w);
        fu[2] = pk2(b.x, b.y); fu[3] = pk2(b.z, b.w);
        xfrag[ks] = f;
    }

    v4f outAcc[4];
#pragma unroll
    for (int i = 0; i < 4; ++i) outAcc[i] = (v4f){0.f,0.f,0.f,0.f};

    const float scale = 0.17677669529663687f;   // 1/sqrt(32)
    const v4f vzero = (v4f){0.f,0.f,0.f,0.f};
    u16* ps = &sm[o_ps + (w*16)*PSP];           // this wave's P-slice buffer

#pragma unroll 1
    for (int h = 0; h < Hh; ++h) {
        // barrier 1: prev head's cross-wave K/V^T reads complete before overwrite
        __syncthreads();

        // ===== Q^T proj: MFMA(Wq^T, X) -> D[ch][qrow]; lane = 4 consecutive ch =====
        {
            const u16* wb = wql + h*2048;
#pragma unroll
            for (int nt = 0; nt < 2; ++nt) {
                v4f acc = vzero;
#pragma unroll
                for (int ks = 0; ks < 2; ++ks) {
                    v8s wf = *reinterpret_cast<const v8s*>(wb + (nt*16+l15)*64 + ks*32 + quad*8);
                    acc = MFMA(wf, xfrag[ks], acc);
                }
                float4 b4 = *reinterpret_cast<const float4*>(bq + h*32 + nt*16 + quad*4);
                u32 lo = pk2((acc[0]+b4.x)*scale, (acc[1]+b4.y)*scale);
                u32 hi = pk2((acc[2]+b4.z)*scale, (acc[3]+b4.w)*scale);
                *reinterpret_cast<uint2*>(&sm[o_q + (w*16+l15)*QP + nt*16 + quad*4]) = make_uint2(lo, hi);
            }
        }
        // ===== K^T proj =====
        {
            const u16* wb = wkl + h*2048;
#pragma unroll
            for (int nt = 0; nt < 2; ++nt) {
                v4f acc = vzero;
#pragma unroll
                for (int ks = 0; ks < 2; ++ks) {
                    v8s wf = *reinterpret_cast<const v8s*>(wb + (nt*16+l15)*64 + ks*32 + quad*8);
                    acc = MFMA(wf, xfrag[ks], acc);
                }
                float4 b4 = *reinterpret_cast<const float4*>(bk + h*32 + nt*16 + quad*4);
                u32 lo = pk2(acc[0]+b4.x, acc[1]+b4.y);
                u32 hi = pk2(acc[2]+b4.z, acc[3]+b4.w);
                *reinterpret_cast<uint2*>(&sm[o_k + (w*16+l15)*QP + nt*16 + quad*4]) = make_uint2(lo, hi);
            }
        }
        // ===== V proj (non-transposed): D[krow][ch] -> V^T via b64 pack =====
        {
            const u16* wb = wvl + h*2048;
#pragma unroll
            for (int nt = 0; nt < 2; ++nt) {
                v4f acc = vzero;
#pragma unroll
                for (int ks = 0; ks < 2; ++ks) {
                    v8s wf = *reinterpret_cast<const v8s*>(wb + (nt*16+l15)*64 + ks*32 + quad*8);
                    acc = MFMA(xfrag[ks], wf, acc);
                }
                float bias = bv[h*32 + nt*16 + l15];
                u32 lo = pk2(acc[0]+bias, acc[1]+bias);
                u32 hi = pk2(acc[2]+bias, acc[3]+bias);
                int ch = nt*16 + l15;
                *reinterpret_cast<uint2*>(&sm[o_vt + ch*NRp + w*16 + quad*4]) = make_uint2(lo, hi);
            }
        }
        // barrier 2: K, V^T (cross-wave operands) visible
        __syncthreads();

        // ===== S^T = MFMA(K, Q) -> D[krow][qrow]; lane: qrow=l15, 4 consec krows =====
        v8s qf = *reinterpret_cast<const v8s*>(&sm[o_q + (w*16+l15)*QP + quad*8]);   // own-wave
        v4f S[W];
#pragma unroll
        for (int ct = 0; ct < W; ++ct) {
            v8s kf = *reinterpret_cast<const v8s*>(&sm[o_k + (ct*16+l15)*QP + quad*8]);
            S[ct] = MFMA(kf, qf, vzero);
        }
        // ===== softmax over keys (per-lane row; reduce in-reg then xor 16,32) =====
        float mm = S[0][0];
#pragma unroll
        for (int ct = 0; ct < W; ++ct)
#pragma unroll
            for (int r = 0; r < 4; ++r) mm = fmaxf(mm, S[ct][r]);
        mm = fmaxf(mm, __shfl_xor(mm, 16));
        mm = fmaxf(mm, __shfl_xor(mm, 32));
        float ss = 0.f;
#pragma unroll
        for (int ct = 0; ct < W; ++ct)
#pragma unroll
            for (int r = 0; r < 4; ++r) { float p = __expf(S[ct][r] - mm); S[ct][r] = p; ss += p; }
        ss += __shfl_xor(ss, 16);
        ss += __shfl_xor(ss, 32);
        float rl = 1.f / ss;

        // ===== O^T = MFMA(V^T, P) with per-ks wave-private P transpose =====
        v4f Oacc[2] = { vzero, vzero };
#pragma unroll
        for (int ks = 0; ks < W/2; ++ks) {
#pragma unroll
            for (int half = 0; half < 2; ++half) {
                int ct = 2*ks + half;
                u32 lo = pk2(S[ct][0]*rl, S[ct][1]*rl);
                u32 hi = pk2(S[ct][2]*rl, S[ct][3]*rl);
                *reinterpret_cast<uint2*>(&ps[l15*PSP + half*16 + quad*4]) = make_uint2(lo, hi);
            }
            v8s pf = *reinterpret_cast<const v8s*>(&ps[l15*PSP + quad*8]);   // in-wave RAW, HW-ordered
#pragma unroll
            for (int nt = 0; nt < 2; ++nt) {
                v8s vf = *reinterpret_cast<const v8s*>(&sm[o_vt + (nt*16+l15)*NRp + ks*32 + quad*8]);
                Oacc[nt] = MFMA(vf, pf, Oacc[nt]);
            }
        }
        // O into Q container (own-wave row; qf already consumed)
#pragma unroll
        for (int nt = 0; nt < 2; ++nt) {
            u32 lo = pk2(Oacc[nt][0], Oacc[nt][1]);
            u32 hi = pk2(Oacc[nt][2], Oacc[nt][3]);
            *reinterpret_cast<uint2*>(&sm[o_q + (w*16+l15)*QP + nt*16 + quad*4]) = make_uint2(lo, hi);
        }

        // ===== out^T += MFMA(Wo^T, O) -> D[d][qrow]; lane = 4 consec d =====
        v8s of = *reinterpret_cast<const v8s*>(&sm[o_q + (w*16+l15)*QP + quad*8]);   // own-wave
        {
            const u16* wb = wol + h*2048;
#pragma unroll
            for (int nt = 0; nt < 4; ++nt) {
                v8s wf = *reinterpret_cast<const v8s*>(wb + (nt*16+l15)*32 + quad*8);
                outAcc[nt] = MFMA(wf, of, outAcc[nt]);
            }
        }
    }

    // ===== epilogue: lane owns row w*16+l15, d = nt*16+quad*4 .. +3 (float4) =====
    float* orow = out + base + (w*16 + l15)*rstride;
#pragma unroll
    for (int nt = 0; nt < 4; ++nt) {
        int d0 = nt*16 + quad*4;
        float4 b4 = *reinterpret_cast<const float4*>(bo + d0);
        float4 v = make_float4(outAcc[nt][0]+b4.x, outAcc[nt][1]+b4.y,
                               outAcc[nt][2]+b4.z, outAcc[nt][3]+b4.w);
        if (MODE == 1) {
            float4 p = *reinterpret_cast<const float4*>(orow + d0);
            v.x += p.x; v.y += p.y; v.z += p.z; v.w += p.w;
        }
        *reinterpret_cast<float4*>(orow + d0) = v;
    }
}

extern "C" void kernel_launch(void* const* d_in, const int* in_sizes, int n_in,
                              void* d_out, int out_size, void* d_ws, size_t ws_size,
                              hipStream_t stream) {
    const float* x   = (const float*)d_in[0];
    const float* tqw = (const float*)d_in[1];  const float* tqb = (const float*)d_in[2];
    const float* tkw = (const float*)d_in[3];  const float* tkb = (const float*)d_in[4];
    const float* tvw = (const float*)d_in[5];  const float* tvb = (const float*)d_in[6];
    const float* fqw = (const float*)d_in[7];  const float* fqb = (const float*)d_in[8];
    const float* fkw = (const float*)d_in[9];  const float* fkb = (const float*)d_in[10];
    const float* fvw = (const float*)d_in[11]; const float* fvb = (const float*)d_in[12];
    const float* tow = (const float*)d_in[13]; const float* tob = (const float*)d_in[14];
    const float* fow = (const float*)d_in[15]; const float* fob = (const float*)d_in[16];
    float* out = (float*)d_out;
    u16* ws = (u16*)d_ws;   // 128 KB

    hipLaunchKernelGGL(prep_weights, dim3(256), dim3(256), 0, stream,
                       tqw, tkw, tvw, fqw, fkw, fvw, tow, fow, ws);
    hipLaunchKernelGGL((axial_mfma<64,0>), dim3(Bb*Ff), dim3(256), 0, stream,
                       x, ws, tqb, tkb, tvb, tob, out);
    hipLaunchKernelGGL((axial_mfma<128,1>), dim3(Bb*Tt), dim3(512), 0, stream,
                       x, ws, fqb, fkb, fvb, fob, out);
}

// Round 8
// 381.833 us; speedup vs baseline: 1.2676x; 1.2676x over previous
//
#include <hip/hip_runtime.h>

typedef unsigned short u16;
typedef unsigned int   u32;
typedef short v8s __attribute__((ext_vector_type(8)));   // 8 bf16 (A/B frag, 4 VGPR)
typedef float v4f __attribute__((ext_vector_type(4)));   // 4 fp32 (C/D frag)

#define DEV __device__ __forceinline__
#define MFMA(a,b,c) __builtin_amdgcn_mfma_f32_16x16x32_bf16((a),(b),(c),0,0,0)

constexpr int Bb = 32, Tt = 64, Ff = 128, Dd = 64, Hh = 4, Kk = 32;

DEV u16 f2b(float f) {                       // RNE (prep kernel only)
    u32 u = __float_as_uint(f);
    return (u16)((u + 0x7fffu + ((u >> 16) & 1u)) >> 16);
}
DEV u32 pk2(float a, float b) {              // round-half-up pair pack (2 bf16 in u32)
    u32 x = __float_as_uint(a) + 0x8000u;
    u32 y = __float_as_uint(b) + 0x8000u;
    return (x >> 16) | (y & 0xffff0000u);
}

// ---- prep: convert all weights to bf16 containers in ws (128 KB) ----
// ws layout (u16):
//   [0, 49152)      : 6 proj  x [h][ch=32][d=64]   (tq,tk,tv,fq,fk,fv)
//   [49152, 65536)  : 2 woT   x [h][d=64][k=32]    (to, fo)
__global__ __launch_bounds__(256)
void prep_weights(const float* __restrict__ tq, const float* __restrict__ tk,
                  const float* __restrict__ tv, const float* __restrict__ fq,
                  const float* __restrict__ fk, const float* __restrict__ fv,
                  const float* __restrict__ to_, const float* __restrict__ fo,
                  u16* __restrict__ ws)
{
    int idx = blockIdx.x * 256 + threadIdx.x;          // 0..65535
    if (idx < 49152) {
        int p = idx >> 13, rem = idx & 8191;           // [h][ch][d]
        int h = rem >> 11, ch = (rem >> 6) & 31, d = rem & 63;
        const float* w = (p==0)?tq:(p==1)?tk:(p==2)?tv:(p==3)?fq:(p==4)?fk:fv;
        ws[idx] = f2b(w[d*128 + h*32 + ch]);           // w[d][h][ch]
    } else {
        int i2 = idx - 49152;
        int path = i2 >> 13, rem = i2 & 8191;          // [h][d][k]
        int h = rem >> 11, d = (rem >> 5) & 63, k2 = rem & 31;
        const float* w = path ? fo : to_;
        ws[idx] = f2b(w[h*2048 + k2*64 + d]);          // wo[h][k][d]
    }
}

// Fragment facts (HW-verified, learn_hip m89/m120):
//   A-frag: lane = A[m][k], m=lane&15, k=quad*8+j  (container row-major [m][k])
//   B-frag: lane = B[k][n], n=lane&15, k=quad*8+j  (container [n][k])
//   C/D:    lane = D[row][col], col=lane&15, row=quad*4+r
//   MFMA(A,B) -> D[m][n] = sum_k A[m][k]*B[n][k]; operand swap transposes D.
// MODE 0: temporal (NR=64 rows=T, block per (b,f)), writes fp32 partial.
// MODE 1: feature (NR=128 rows=F, block per (b,t)), read-add-write final.
// NOTE: no min-waves-per-EU bound — round 7's (NR*4, 8) forced VGPR=32 and
// spilled ~670 MB to scratch (FETCH 66->349 MB, WRITE 65->454 MB). Natural
// allocation is ~56 VGPR, already under the 64-VGPR / 8-wave-per-SIMD cliff.
template<int NR, int MODE>
__global__ __launch_bounds__(NR*4)
void axial_mfma(const float* __restrict__ x, const u16* __restrict__ wsw,
                const float* __restrict__ bq, const float* __restrict__ bk,
                const float* __restrict__ bv, const float* __restrict__ bo,
                float* __restrict__ out)
{
    constexpr int W   = NR / 16;      // waves per block
    constexpr int QP  = 40;           // Q/K/O row pitch (80B: 16B-aligned)
    constexpr int NRp = NR + 8;       // V^T pitch (16B-aligned)
    constexpr int PSP = 40;           // P-slice row pitch
    constexpr int o_q  = 0;                   // Q, reused as O  [NR][QP]  (own-wave rows)
    constexpr int o_k  = o_q + NR * QP;       // K    [NR][QP]
    constexpr int o_vt = o_k + NR * QP;       // V^T  [32][NRp]
    constexpr int o_ps = o_vt + 32 * NRp;     // P-slice [W][16][PSP]  (wave-private)
    constexpr int SMEM = o_ps + W * 16 * PSP; // feature: 39424 B, temporal: 19968 B
    __shared__ alignas(16) u16 sm[SMEM];

    const int tid  = threadIdx.x;
    const int w    = tid >> 6;
    const int lane = tid & 63;
    const int quad = lane >> 4;
    const int l15  = lane & 15;
    const int bid  = blockIdx.x;

    int base, rstride;
    if (MODE == 0) { int b = bid >> 7, f = bid & 127; base = b*(Tt*Ff*Dd) + f*Dd; rstride = Ff*Dd; }
    else           { base = bid * (Ff*Dd); rstride = Dd; }

    constexpr int PB = (MODE == 0) ? 0 : 3;
    const u16* wql = wsw + (PB+0)*8192;
    const u16* wkl = wsw + (PB+1)*8192;
    const u16* wvl = wsw + (PB+2)*8192;
    const u16* wol = wsw + 49152 + MODE*8192;

    // ---- X fragments (A/B dual-use; same lane mapping), row w*16+l15 ----
    v8s xfrag[2];
#pragma unroll
    for (int ks = 0; ks < 2; ++ks) {
        const float* xp = x + base + (w*16 + l15)*rstride + ks*32 + quad*8;
        float4 a = *reinterpret_cast<const float4*>(xp);
        float4 b = *reinterpret_cast<const float4*>(xp + 4);
        v8s f;
        u32* fu = reinterpret_cast<u32*>(&f);
        fu[0] = pk2(a.x, a.y); fu[1] = pk2(a.z, a.w);
        fu[2] = pk2(b.x, b.y); fu[3] = pk2(b.z, b.w);
        xfrag[ks] = f;
    }

    v4f outAcc[4];
#pragma unroll
    for (int i = 0; i < 4; ++i) outAcc[i] = (v4f){0.f,0.f,0.f,0.f};

    const float scale = 0.17677669529663687f;   // 1/sqrt(32)
    const v4f vzero = (v4f){0.f,0.f,0.f,0.f};
    u16* ps = &sm[o_ps + (w*16)*PSP];           // this wave's P-slice buffer

#pragma unroll 1
    for (int h = 0; h < Hh; ++h) {
        // barrier 1: prev head's cross-wave K/V^T reads complete before overwrite
        __syncthreads();

        // ===== Q^T proj: MFMA(Wq^T, X) -> D[ch][qrow]; lane = 4 consecutive ch =====
        {
            const u16* wb = wql + h*2048;
#pragma unroll
            for (int nt = 0; nt < 2; ++nt) {
                v4f acc = vzero;
#pragma unroll
                for (int ks = 0; ks < 2; ++ks) {
                    v8s wf = *reinterpret_cast<const v8s*>(wb + (nt*16+l15)*64 + ks*32 + quad*8);
                    acc = MFMA(wf, xfrag[ks], acc);
                }
                float4 b4 = *reinterpret_cast<const float4*>(bq + h*32 + nt*16 + quad*4);
                u32 lo = pk2((acc[0]+b4.x)*scale, (acc[1]+b4.y)*scale);
                u32 hi = pk2((acc[2]+b4.z)*scale, (acc[3]+b4.w)*scale);
                *reinterpret_cast<uint2*>(&sm[o_q + (w*16+l15)*QP + nt*16 + quad*4]) = make_uint2(lo, hi);
            }
        }
        // ===== K^T proj =====
        {
            const u16* wb = wkl + h*2048;
#pragma unroll
            for (int nt = 0; nt < 2; ++nt) {
                v4f acc = vzero;
#pragma unroll
                for (int ks = 0; ks < 2; ++ks) {
                    v8s wf = *reinterpret_cast<const v8s*>(wb + (nt*16+l15)*64 + ks*32 + quad*8);
                    acc = MFMA(wf, xfrag[ks], acc);
                }
                float4 b4 = *reinterpret_cast<const float4*>(bk + h*32 + nt*16 + quad*4);
                u32 lo = pk2(acc[0]+b4.x, acc[1]+b4.y);
                u32 hi = pk2(acc[2]+b4.z, acc[3]+b4.w);
                *reinterpret_cast<uint2*>(&sm[o_k + (w*16+l15)*QP + nt*16 + quad*4]) = make_uint2(lo, hi);
            }
        }
        // ===== V proj (non-transposed): D[krow][ch] -> V^T via b64 pack =====
        {
            const u16* wb = wvl + h*2048;
#pragma unroll
            for (int nt = 0; nt < 2; ++nt) {
                v4f acc = vzero;
#pragma unroll
                for (int ks = 0; ks < 2; ++ks) {
                    v8s wf = *reinterpret_cast<const v8s*>(wb + (nt*16+l15)*64 + ks*32 + quad*8);
                    acc = MFMA(xfrag[ks], wf, acc);
                }
                float bias = bv[h*32 + nt*16 + l15];
                u32 lo = pk2(acc[0]+bias, acc[1]+bias);
                u32 hi = pk2(acc[2]+bias, acc[3]+bias);
                int ch = nt*16 + l15;
                *reinterpret_cast<uint2*>(&sm[o_vt + ch*NRp + w*16 + quad*4]) = make_uint2(lo, hi);
            }
        }
        // barrier 2: K, V^T (cross-wave operands) visible
        __syncthreads();

        // ===== S^T = MFMA(K, Q) -> D[krow][qrow]; lane: qrow=l15, 4 consec krows =====
        v8s qf = *reinterpret_cast<const v8s*>(&sm[o_q + (w*16+l15)*QP + quad*8]);   // own-wave
        v4f S[W];
#pragma unroll
        for (int ct = 0; ct < W; ++ct) {
            v8s kf = *reinterpret_cast<const v8s*>(&sm[o_k + (ct*16+l15)*QP + quad*8]);
            S[ct] = MFMA(kf, qf, vzero);
        }
        // ===== softmax over keys (per-lane row; reduce in-reg then xor 16,32) =====
        float mm = S[0][0];
#pragma unroll
        for (int ct = 0; ct < W; ++ct)
#pragma unroll
            for (int r = 0; r < 4; ++r) mm = fmaxf(mm, S[ct][r]);
        mm = fmaxf(mm, __shfl_xor(mm, 16));
        mm = fmaxf(mm, __shfl_xor(mm, 32));
        float ss = 0.f;
#pragma unroll
        for (int ct = 0; ct < W; ++ct)
#pragma unroll
            for (int r = 0; r < 4; ++r) { float p = __expf(S[ct][r] - mm); S[ct][r] = p; ss += p; }
        ss += __shfl_xor(ss, 16);
        ss += __shfl_xor(ss, 32);
        float rl = 1.f / ss;

        // ===== O^T = MFMA(V^T, P) with per-ks wave-private P transpose =====
        v4f Oacc[2] = { vzero, vzero };
#pragma unroll
        for (int ks = 0; ks < W/2; ++ks) {
#pragma unroll
            for (int half = 0; half < 2; ++half) {
                int ct = 2*ks + half;
                u32 lo = pk2(S[ct][0]*rl, S[ct][1]*rl);
                u32 hi = pk2(S[ct][2]*rl, S[ct][3]*rl);
                *reinterpret_cast<uint2*>(&ps[l15*PSP + half*16 + quad*4]) = make_uint2(lo, hi);
            }
            v8s pf = *reinterpret_cast<const v8s*>(&ps[l15*PSP + quad*8]);   // in-wave RAW, HW-ordered
#pragma unroll
            for (int nt = 0; nt < 2; ++nt) {
                v8s vf = *reinterpret_cast<const v8s*>(&sm[o_vt + (nt*16+l15)*NRp + ks*32 + quad*8]);
                Oacc[nt] = MFMA(vf, pf, Oacc[nt]);
            }
        }
        // O into Q container (own-wave row; qf already consumed)
#pragma unroll
        for (int nt = 0; nt < 2; ++nt) {
            u32 lo = pk2(Oacc[nt][0], Oacc[nt][1]);
            u32 hi = pk2(Oacc[nt][2], Oacc[nt][3]);
            *reinterpret_cast<uint2*>(&sm[o_q + (w*16+l15)*QP + nt*16 + quad*4]) = make_uint2(lo, hi);
        }

        // ===== out^T += MFMA(Wo^T, O) -> D[d][qrow]; lane = 4 consec d =====
        v8s of = *reinterpret_cast<const v8s*>(&sm[o_q + (w*16+l15)*QP + quad*8]);   // own-wave
        {
            const u16* wb = wol + h*2048;
#pragma unroll
            for (int nt = 0; nt < 4; ++nt) {
                v8s wf = *reinterpret_cast<const v8s*>(wb + (nt*16+l15)*32 + quad*8);
                outAcc[nt] = MFMA(wf, of, outAcc[nt]);
            }
        }
    }

    // ===== epilogue: lane owns row w*16+l15, d = nt*16+quad*4 .. +3 (float4) =====
    float* orow = out + base + (w*16 + l15)*rstride;
#pragma unroll
    for (int nt = 0; nt < 4; ++nt) {
        int d0 = nt*16 + quad*4;
        float4 b4 = *reinterpret_cast<const float4*>(bo + d0);
        float4 v = make_float4(outAcc[nt][0]+b4.x, outAcc[nt][1]+b4.y,
                               outAcc[nt][2]+b4.z, outAcc[nt][3]+b4.w);
        if (MODE == 1) {
            float4 p = *reinterpret_cast<const float4*>(orow + d0);
            v.x += p.x; v.y += p.y; v.z += p.z; v.w += p.w;
        }
        *reinterpret_cast<float4*>(orow + d0) = v;
    }
}

extern "C" void kernel_launch(void* const* d_in, const int* in_sizes, int n_in,
                              void* d_out, int out_size, void* d_ws, size_t ws_size,
                              hipStream_t stream) {
    const float* x   = (const float*)d_in[0];
    const float* tqw = (const float*)d_in[1];  const float* tqb = (const float*)d_in[2];
    const float* tkw = (const float*)d_in[3];  const float* tkb = (const float*)d_in[4];
    const float* tvw = (const float*)d_in[5];  const float* tvb = (const float*)d_in[6];
    const float* fqw = (const float*)d_in[7];  const float* fqb = (const float*)d_in[8];
    const float* fkw = (const float*)d_in[9];  const float* fkb = (const float*)d_in[10];
    const float* fvw = (const float*)d_in[11]; const float* fvb = (const float*)d_in[12];
    const float* tow = (const float*)d_in[13]; const float* tob = (const float*)d_in[14];
    const float* fow = (const float*)d_in[15]; const float* fob = (const float*)d_in[16];
    float* out = (float*)d_out;
    u16* ws = (u16*)d_ws;   // 128 KB

    hipLaunchKernelGGL(prep_weights, dim3(256), dim3(256), 0, stream,
                       tqw, tkw, tvw, fqw, fkw, fvw, tow, fow, ws);
    hipLaunchKernelGGL((axial_mfma<64,0>), dim3(Bb*Ff), dim3(256), 0, stream,
                       x, ws, tqb, tkb, tvb, tob, out);
    hipLaunchKernelGGL((axial_mfma<128,1>), dim3(Bb*Tt), dim3(512), 0, stream,
                       x, ws, fqb, fkb, fvb, fob, out);
}